// Round 14
// baseline (942.233 us; speedup 1.0000x reference)
//
#include <hip/hip_runtime.h>

// GRU: B=256, T=2048, I=2, H=128. One workgroup per batch element.
// R14 = R13 (best: 922 us) + critical-path schedule shaping (no structure
// change). R13 structure frozen: NT=256 (4 waves, 1/SIMD), thread
// (q=tid&3, jp=tid>>2) owns gates {r,z,n} x units {jp, 64+jp}, cols
// [32q,32q+32); fp16 h in LDS (fp32 recurrence on producers), prescaled
// fp16 weights + v_dot2_f32_f16; xp/bhn folded into acc init (x1/4);
// non-volatile single-instr v_add_f32_dpp quad butterfly; exp2/rcp gates;
// one barrier/step; 40-half slice stride (conflict-free quad broadcast).
// R14 deltas:
//  (1) gate-major dot ordering: (aR0,aR1,aZ0,aZ1)x16 -> butterfly+exp2/rcp
//      of r,z -> n-dots as 4 chains of 8. The r/z transcendental latency
//      (~50 cyc) hides under the n-dot issue; the post-dot tail shrinks to
//      fma->exp2->rcp->fma (~45 cyc).
//  (2) double buffer via pointer swap (no per-access buffer-select math).
//  (3) h-reads issued first after the barrier; x-prefetch/acc-inits placed
//      in the read-latency shadow.
// Decision rule: <2% gain => declare latency-floor ceiling (makespan =
// 2048 steps x single-wave path; co-scheduling/MFMA variants analyzed and
// rejected in journal — they add issue or redistribution, never shorten
// the longest sequence's path).
// Falsified (do not revisit): 16-col/8-lane-reduce (R4/R6/R10); VGPR
// residency forcing (R3/R8); volatile DPP fences (R4/R6).

#define BB 256
#define TT 2048
#define HH 128
#define NT 256
#define HHALFS 160   // per buffer: 4 slices x 40 halfs (32 data + 8 pad)

typedef _Float16 v2h __attribute__((ext_vector_type(2)));
typedef _Float16 v8h __attribute__((ext_vector_type(8)));

// x += dpp(x) in one v_add_f32_dpp; s_nop 1 covers the VALU->DPP hazard.
// Non-volatile: schedulable.
#define DPP_ADD_Q(x, QPSTR) do { float _d;                                   \
    asm("s_nop 1\n\t"                                                        \
        "v_add_f32_dpp %0, %1, %1 " QPSTR " row_mask:0xf bank_mask:0xf"      \
        : "=v"(_d) : "v"(x));                                                \
    (x) = _d; } while (0)

__global__ __launch_bounds__(NT, 1) void gru_seq_kernel(
    const float* __restrict__ x,        // [B, T, 2]
    const int*   __restrict__ lengths,  // [B]
    const float* __restrict__ W_ih,     // [384, 2]
    const float* __restrict__ W_hh,     // [384, 128]
    const float* __restrict__ b_ih,     // [384]
    const float* __restrict__ b_hh,     // [384]
    const float* __restrict__ head_w,   // [128]
    const float* __restrict__ head_b,   // [1]
    float* __restrict__ out)            // [B]
{
    __shared__ __align__(16) float x_lds[(TT + 1) * 2];      // 16 KB (+prefetch)
    __shared__ __align__(16) _Float16 h_lds[2][HHALFS];      // 640 B
    __shared__ float red[HH];

    const int tid = threadIdx.x;
    const int q  = tid & 3;          // 32-col slice
    const int jp = tid >> 2;         // unit-pair index 0..63
    const int b  = blockIdx.x;
    const int len = lengths[b];

    const float S_RZ = -1.4426950408889634f;   // -log2(e)
    const float S_N  =  2.8853900817779268f;   //  2*log2(e)

    // --- weights: 6 rows (g x p) x 32-col slice q, prescaled fp16 ---
    v2h wv[6][16];
    #pragma unroll
    for (int g = 0; g < 3; ++g) {
        const float s = (g == 2) ? S_N : S_RZ;
        #pragma unroll
        for (int p = 0; p < 2; ++p) {
            const float4* Wp = (const float4*)(W_hh + (size_t)(g * HH + 64 * p + jp) * HH + 32 * q);
            #pragma unroll
            for (int i = 0; i < 8; ++i) {
                const float4 w4 = Wp[i];
                wv[g * 2 + p][2 * i]     = (v2h){(_Float16)(s * w4.x), (_Float16)(s * w4.y)};
                wv[g * 2 + p][2 * i + 1] = (v2h){(_Float16)(s * w4.z), (_Float16)(s * w4.w)};
            }
        }
    }

    // --- all-lane init constants (x 1/4: quad butterfly sums 4 replicas) ---
    float wir0[2], wir1[2], br4[2], wiz0[2], wiz1[2], bz4[2], bhn4[2];
    #pragma unroll
    for (int p = 0; p < 2; ++p) {
        const int u = 64 * p + jp;
        const float s4 = S_RZ * 0.25f;
        wir0[p] = s4 * W_ih[u * 2];        wir1[p] = s4 * W_ih[u * 2 + 1];
        br4[p]  = s4 * (b_ih[u] + b_hh[u]);
        wiz0[p] = s4 * W_ih[(HH + u) * 2]; wiz1[p] = s4 * W_ih[(HH + u) * 2 + 1];
        bz4[p]  = s4 * (b_ih[HH + u] + b_hh[HH + u]);
        bhn4[p] = (S_N * 0.25f) * b_hh[2 * HH + u];
    }

    // --- per-lane consumer unit: uSel = 64*(q&1) + jp ---
    const int pSel = q & 1;
    const int uSel = 64 * pSel + jp;
    const float win0 = S_N * W_ih[(2 * HH + uSel) * 2];
    const float win1 = S_N * W_ih[(2 * HH + uSel) * 2 + 1];
    const float bn   = S_N * b_ih[2 * HH + uSel];
    const float hw   = head_w[uSel];
    const int wrOff  = 40 * (uSel >> 5) + (uSel & 31);   // write slot (halfs)
    const int rdOff  = 40 * q;                            // read slice base

    // --- stage x[b] into LDS (float4, coalesced) ---
    {
        const float4* xb4 = (const float4*)(x + (size_t)b * TT * 2);
        float4* xl4 = (float4*)x_lds;
        #pragma unroll
        for (int i = tid; i < TT * 2 / 4; i += NT) xl4[i] = xb4[i];
    }
    if (tid == 0) { x_lds[TT * 2] = 0.f; x_lds[TT * 2 + 1] = 0.f; }
    for (int i = tid; i < 2 * HHALFS; i += NT) ((_Float16*)h_lds)[i] = (_Float16)0.f;

    __syncthreads();

    float h_reg = 0.0f;   // fp32 h[uSel]; live on lanes q<2
    const _Float16* __restrict__ hrd = &h_lds[0][0];
    _Float16* __restrict__ hwr = &h_lds[1][0];
    const float2* x2 = (const float2*)x_lds;
    float2 xt = x2[0];

    for (int t = 0; t < len; ++t) {
        // (1) issue h-reads immediately after the barrier
        const v8h* hb = (const v8h*)(hrd + rdOff);
        v8h hv[4];
        #pragma unroll
        for (int i = 0; i < 4; ++i) hv[i] = hb[i];

        // (3) latency shadow: x prefetch + acc inits (independent of h)
        const float2 xt_next = x2[t + 1];
        float aR0 = fmaf(wir0[0], xt.x, fmaf(wir1[0], xt.y, br4[0]));
        float aR1 = fmaf(wir0[1], xt.x, fmaf(wir1[1], xt.y, br4[1]));
        float aZ0 = fmaf(wiz0[0], xt.x, fmaf(wiz1[0], xt.y, bz4[0]));
        float aZ1 = fmaf(wiz0[1], xt.x, fmaf(wiz1[1], xt.y, bz4[1]));
        const float xn = fmaf(win0, xt.x, fmaf(win1, xt.y, bn));

        v2h h2[16];
        #pragma unroll
        for (int i = 0; i < 4; ++i) {
            h2[4*i+0] = __builtin_shufflevector(hv[i], hv[i], 0, 1);
            h2[4*i+1] = __builtin_shufflevector(hv[i], hv[i], 2, 3);
            h2[4*i+2] = __builtin_shufflevector(hv[i], hv[i], 4, 5);
            h2[4*i+3] = __builtin_shufflevector(hv[i], hv[i], 6, 7);
        }

        // block 1: r/z dots, 4-way ILP
        #pragma unroll
        for (int i = 0; i < 16; ++i) {
            aR0 = __builtin_amdgcn_fdot2(wv[0][i], h2[i], aR0, false);
            aR1 = __builtin_amdgcn_fdot2(wv[1][i], h2[i], aR1, false);
            aZ0 = __builtin_amdgcn_fdot2(wv[2][i], h2[i], aZ0, false);
            aZ1 = __builtin_amdgcn_fdot2(wv[3][i], h2[i], aZ1, false);
        }

        // butterfly + trans for r/z NOW — hides under n-dot issue below
        DPP_ADD_Q(aR0, "quad_perm:[1,0,3,2]");
        DPP_ADD_Q(aR1, "quad_perm:[1,0,3,2]");
        DPP_ADD_Q(aZ0, "quad_perm:[1,0,3,2]");
        DPP_ADD_Q(aZ1, "quad_perm:[1,0,3,2]");
        DPP_ADD_Q(aR0, "quad_perm:[2,3,0,1]");
        DPP_ADD_Q(aR1, "quad_perm:[2,3,0,1]");
        DPP_ADD_Q(aZ0, "quad_perm:[2,3,0,1]");
        DPP_ADD_Q(aZ1, "quad_perm:[2,3,0,1]");
        const float ar = pSel ? aR1 : aR0;
        const float az = pSel ? aZ1 : aZ0;
        const float r = __builtin_amdgcn_rcpf(1.f + __builtin_amdgcn_exp2f(ar));
        const float z = __builtin_amdgcn_rcpf(1.f + __builtin_amdgcn_exp2f(az));

        // block 2: n dots as 4 chains of 8 (4-way ILP)
        float aN0a = bhn4[0], aN0b = 0.f, aN1a = bhn4[1], aN1b = 0.f;
        #pragma unroll
        for (int i = 0; i < 8; ++i) {
            aN0a = __builtin_amdgcn_fdot2(wv[4][i],     h2[i],     aN0a, false);
            aN0b = __builtin_amdgcn_fdot2(wv[4][i + 8], h2[i + 8], aN0b, false);
            aN1a = __builtin_amdgcn_fdot2(wv[5][i],     h2[i],     aN1a, false);
            aN1b = __builtin_amdgcn_fdot2(wv[5][i + 8], h2[i + 8], aN1b, false);
        }
        float aN0 = aN0a + aN0b;
        float aN1 = aN1a + aN1b;
        DPP_ADD_Q(aN0, "quad_perm:[1,0,3,2]");
        DPP_ADD_Q(aN1, "quad_perm:[1,0,3,2]");
        DPP_ADD_Q(aN0, "quad_perm:[2,3,0,1]");
        DPP_ADD_Q(aN1, "quad_perm:[2,3,0,1]");
        const float an = pSel ? aN1 : aN0;

        // n tail: fma -> exp2 -> rcp -> fma -> update (r,z already ready)
        const float u = __builtin_amdgcn_exp2f(fmaf(r, an, xn));
        const float n = fmaf(-2.f, __builtin_amdgcn_rcpf(1.f + u), 1.f);
        const float h_new = n + z * (h_reg - n);
        if (q < 2) {
            h_reg = h_new;
            hwr[wrOff] = (_Float16)h_new;
        }
        __syncthreads();
        // (2) pointer-swap double buffer
        const _Float16* tmp = hrd; hrd = hwr; hwr = (_Float16*)tmp;
        xt = xt_next;
    }

    // --- head: out[b] = dot(h, head_w) + head_b ---
    if (q < 2) red[uSel] = h_reg * hw;
    __syncthreads();
    if (tid < 64) {
        float v = red[tid] + red[tid + 64];
        #pragma unroll
        for (int off = 32; off > 0; off >>= 1) v += __shfl_xor(v, off, 64);
        if (tid == 0) out[b] = v + head_b[0];
    }
}

extern "C" void kernel_launch(void* const* d_in, const int* in_sizes, int n_in,
                              void* d_out, int out_size, void* d_ws, size_t ws_size,
                              hipStream_t stream) {
    const float* x      = (const float*)d_in[0];
    const int*   len    = (const int*)  d_in[1];
    const float* W_ih   = (const float*)d_in[2];
    const float* W_hh   = (const float*)d_in[3];
    const float* b_ih   = (const float*)d_in[4];
    const float* b_hh   = (const float*)d_in[5];
    const float* head_w = (const float*)d_in[6];
    const float* head_b = (const float*)d_in[7];
    float* out = (float*)d_out;

    gru_seq_kernel<<<BB, NT, 0, stream>>>(x, len, W_ih, W_hh, b_ih, b_hh,
                                          head_w, head_b, out);
}